// Round 6
// baseline (237.583 us; speedup 1.0000x reference)
//
#include <hip/hip_runtime.h>
#include <hip/hip_bf16.h>
#include <stdint.h>

// ---------- types ----------
typedef _Float16 half2v __attribute__((ext_vector_type(2)));
typedef _Float16 half8v __attribute__((ext_vector_type(8)));
typedef uint32_t u32x4  __attribute__((ext_vector_type(4)));
typedef float    f32x4  __attribute__((ext_vector_type(4)));

__device__ __forceinline__ unsigned short f2h(float f) {
  _Float16 h = (_Float16)f;
  return __builtin_bit_cast(unsigned short, h);
}
__device__ __forceinline__ half2v bch2(uint32_t u) {
  return __builtin_bit_cast(half2v, u);
}
__device__ __forceinline__ uint32_t pkrtz_u32(float a, float b) {
  return __builtin_bit_cast(uint32_t, __builtin_amdgcn_cvt_pkrtz(a, b));
}

// Window-major qkv layout. Element index (channel 0 of head n) for pixel (h,w),
// within one tensor's 32MB region (16M f16 elems; includes the half offset).
//  half 0 (horizontal stripes): [b][n][s=h>>3][w][qr=h&7][cc]
//  half 1 (vertical stripes):   [b][n][h][s=w>>3][qr=w&7][cc]  (s*256+qr*32 == w*32)
__device__ __forceinline__ int qkv_idx(int half, int b, int n, int h, int w) {
  int idx = half * 8388608 + (b * 8 + n) * 131072;
  idx += (half == 0) ? ((h >> 3) * 16384 + w * 256 + (h & 7) * 32)
                     : (h * 2048 + w * 32);
  return idx;
}

// async global->LDS, 16 bytes per lane. lbase must be wave-uniform.
#define GLOAD_LDS16(gsrc, lbase)                                          \
  __builtin_amdgcn_global_load_lds(                                       \
      (const __attribute__((address_space(1))) uint32_t*)(gsrc),          \
      (__attribute__((address_space(3))) uint32_t*)(lbase), 16, 0, 0)

// ---------- f32 -> f16 conversion (4 elems/thread) ----------
__global__ __launch_bounds__(256) void cvt_f32_f16(const float* __restrict__ in,
                                                   unsigned short* __restrict__ out,
                                                   int n4) {
  int i = blockIdx.x * 256 + threadIdx.x;
  if (i >= n4) return;
  float4 f = reinterpret_cast<const float4*>(in)[i];
  ushort4 u;
  u.x = f2h(f.x); u.y = f2h(f.y); u.z = f2h(f.z); u.w = f2h(f.w);
  reinterpret_cast<ushort4*>(out)[i] = u;
}

// ---------- f16 GEMM, C[m,n] = sum_k A[m,k]*B[n,k]  (A: MxK, B: NxK row-major)
// 128x128 tile, 4 waves (2x2), each wave 64x64 = 4x4 frags, MFMA 16x16x32 f16.
// T3-lite pipeline: double-buffered LDS (2x BK=32 tiles, 32KB), stage for tile
// t+1 issued BEFORE compute of tile t, ONE barrier per K-step (barrier's
// implicit vmcnt(0) drain is the only wait -> race-free by construction).
// Operand-swapped MFMA epilogue (lane holds 4 contiguous n at one m).
// LDS k-slot XOR swizzle (pre-swizzled global source; linear gload_lds dest).
// MODE 0: f32 out + bias, token-major (GEMM2).
// MODE 1: f16 out scattered to window-major qkv regions (GEMM1, N=1536).
template<int MODE>
__global__ __launch_bounds__(256) void gemm_bt(
    const unsigned short* __restrict__ A,
    const unsigned short* __restrict__ B,
    unsigned short* __restrict__ Cq,
    float* __restrict__ Cf,
    const float* __restrict__ bias,
    int M, int N, int K)
{
  __shared__ unsigned short As[2][128 * 32];
  __shared__ unsigned short Bs[2][128 * 32];
  const int tid  = threadIdx.x;
  const int m0   = blockIdx.x * 128;
  const int n0   = blockIdx.y * 128;
  const int wave = tid >> 6, lane = tid & 63;
  const int wr = wave >> 1, wc = wave & 1;
  const int sr = tid >> 2;                                // staging row 0..63
  const int sc = ((tid & 3) ^ ((tid >> 3) & 3)) * 8;      // pre-swizzled k-chunk
  const size_t aBase0 = (size_t)(m0 + sr) * K + sc;
  const size_t aBase1 = (size_t)(m0 + 64 + sr) * K + sc;
  const size_t bBase0 = (size_t)(n0 + sr) * K + sc;
  const size_t bBase1 = (size_t)(n0 + 64 + sr) * K + sc;
  // per-thread LDS dest is linear tid*16B within each half; wave-uniform base
  char* ldsA0 = (char*)(&As[0][0]) + (tid & ~63) * 16;
  char* ldsA1 = (char*)(&As[1][0]) + (tid & ~63) * 16;
  char* ldsB0 = (char*)(&Bs[0][0]) + (tid & ~63) * 16;
  char* ldsB1 = (char*)(&Bs[1][0]) + (tid & ~63) * 16;

  f32x4 acc[4][4];
  const f32x4 zero = {0.f, 0.f, 0.f, 0.f};
  #pragma unroll
  for (int i = 0; i < 4; ++i)
    #pragma unroll
    for (int j = 0; j < 4; ++j) acc[i][j] = zero;

  const int lr   = lane & 15;
  const int slot = (lane >> 4) ^ ((lr >> 1) & 3);   // swizzled k-slot (elems/8)

#define STAGE_TILE(dA, dB, kofs)                    \
  do {                                              \
    GLOAD_LDS16(A + aBase0 + (kofs), dA);           \
    GLOAD_LDS16(A + aBase1 + (kofs), dA + 4096);    \
    GLOAD_LDS16(B + bBase0 + (kofs), dB);           \
    GLOAD_LDS16(B + bBase1 + (kofs), dB + 4096);    \
  } while (0)

  auto compute = [&](const unsigned short* Asb, const unsigned short* Bsb) {
    half8v af[4], bfr[4];
    #pragma unroll
    for (int i = 0; i < 4; ++i)
      af[i] = *reinterpret_cast<const half8v*>(Asb + (wr * 64 + i * 16 + lr) * 32 + slot * 8);
    #pragma unroll
    for (int j = 0; j < 4; ++j)
      bfr[j] = *reinterpret_cast<const half8v*>(Bsb + (wc * 64 + j * 16 + lr) * 32 + slot * 8);
    #pragma unroll
    for (int i = 0; i < 4; ++i)
      #pragma unroll
      for (int j = 0; j < 4; ++j)
        acc[i][j] = __builtin_amdgcn_mfma_f32_16x16x32_f16(bfr[j], af[i], acc[i][j], 0, 0, 0);
  };

  // prologue: stage tile 0 into buf0; barrier drains it
  STAGE_TILE(ldsA0, ldsB0, 0);
  __syncthreads();

  for (int kt = 0; kt < K; kt += 64) {
    if (kt + 32 < K) STAGE_TILE(ldsA1, ldsB1, kt + 32);   // issue next-tile loads
    compute(&As[0][0], &Bs[0][0]);                        // compute current
    __syncthreads();                                      // buf1 ready; buf0 free
    if (kt + 64 < K) STAGE_TILE(ldsA0, ldsB0, kt + 64);
    compute(&As[1][0], &Bs[1][0]);
    if (kt + 64 < K) __syncthreads();                     // buf0 ready; buf1 free
  }
#undef STAGE_TILE

  // D layout (operand-swapped): row (n-dim) = (lane>>4)*4 + t, col (m-dim) = lane&15
  const int cr = (lane >> 4) * 4;   // channel offset (4 contiguous)
  const int cc = lane & 15;         // token offset

  if constexpr (MODE == 0) {
    #pragma unroll
    for (int j = 0; j < 4; ++j) {
      const int n = n0 + wc * 64 + j * 16 + cr;
      const float4 b4 = *reinterpret_cast<const float4*>(bias + n);
      #pragma unroll
      for (int i = 0; i < 4; ++i) {
        const int m = m0 + wr * 64 + i * 16 + cc;
        float4 r;
        r.x = acc[i][j][0] + b4.x;
        r.y = acc[i][j][1] + b4.y;
        r.z = acc[i][j][2] + b4.z;
        r.w = acc[i][j][3] + b4.w;
        *reinterpret_cast<float4*>(Cf + (size_t)m * N + n) = r;
      }
    }
  } else {
    const int mb   = m0 + wr * 64;    // token base (wave-uniform)
    const int btok = mb >> 12;
    const int htok = (mb >> 6) & 63;
    #pragma unroll
    for (int j = 0; j < 4; ++j) {
      const int nb    = n0 + wc * 64 + j * 16 + cr;  // 4 contiguous channels
      const int tq    = nb >> 9;                     // 0=q 1=k 2=v
      const int halfc = (nb >> 8) & 1;
      const int nn    = (nb & 255) >> 5;
      const int ch4   = nb & 31;
      int base = tq * 16777216 + halfc * 8388608 + (btok * 8 + nn) * 131072 + ch4;
      base += halfc ? (htok * 2048) : ((htok >> 3) * 16384 + (htok & 7) * 32);
      const int wstride = halfc ? 32 : 256;
      #pragma unroll
      for (int i = 0; i < 4; ++i) {
        const int wpix = i * 16 + cc;
        uint2 r;
        r.x = pkrtz_u32(acc[i][j][0], acc[i][j][1]);
        r.y = pkrtz_u32(acc[i][j][2], acc[i][j][3]);
        *reinterpret_cast<uint2*>(Cq + base + wpix * wstride) = r;
      }
    }
  }
}

// ---------- stripe attention + LePE on window-major qkv ----------
// qkvp: q region (32MB) | k region (32MB) | v region (32MB), f16, window-major.
// wlep: f16 LePE weights [half][tap(9)][256].
// outp: token-major 32768 x 512 f16.
__global__ __launch_bounds__(256) void attn_lepe(
    const unsigned short* __restrict__ qkvp,
    const unsigned short* __restrict__ wlep,
    unsigned short* __restrict__ outp)
{
  const int gw   = (int)((blockIdx.x * 256 + threadIdx.x) >> 6);
  const int lane = threadIdx.x & 63;
  const int half = gw >> 15;
  const int id   = gw & 32767;
  const int b    = id >> 12;
  const int n    = (id >> 9) & 7;
  int h0, w0;
  if (half == 0) { const int s = (id >> 6) & 7; h0 = s * 8; w0 = id & 63; }
  else           { const int s = id & 7; h0 = (id >> 3) & 63; w0 = s * 8; }
  const int winbase = qkv_idx(half, b, n, h0, w0);
  const unsigned short* qwin = qkvp + winbase;
  const unsigned short* kwin = qkvp + 16777216 + winbase;
  const unsigned short* vwin = qkvp + 33554432 + winbase;

  // ---- QK^T: lane (qr, kr); window rows are 32-elem contiguous ----
  const int qr = lane >> 3, kr = lane & 7;
  const unsigned short* qp = qwin + qr * 32;
  const unsigned short* kp = kwin + kr * 32;
  float s_val = 0.f;
  #pragma unroll
  for (int c = 0; c < 4; ++c) {
    u32x4 qv = *reinterpret_cast<const u32x4*>(qp + c * 8);
    u32x4 kv = *reinterpret_cast<const u32x4*>(kp + c * 8);
    #pragma unroll
    for (int e = 0; e < 4; ++e)
      s_val = __builtin_amdgcn_fdot2(bch2(qv[e]), bch2(kv[e]), s_val, false);
  }
  s_val *= 0.17677669529663687f;  // 1/sqrt(32)

  // ---- softmax over k within each 8-lane group (|s| small: no max pass) ----
  float p = __expf(s_val);
  float den = p;
  den += __shfl_xor(den, 1);
  den += __shfl_xor(den, 2);
  den += __shfl_xor(den, 4);
  const float a = p * __builtin_amdgcn_rcpf(den);
  const _Float16 ah = (_Float16)a;
  half2v ad = {ah, ah};
  const uint32_t adu = __builtin_bit_cast(uint32_t, ad);

  // ---- PV: lane (qr, d0); v row k is one 64B line for the whole wave ----
  const int d0 = (lane & 7) * 4;
  const int gb = lane & 56;
  half2v o01 = {0, 0}, o23 = {0, 0};
  #pragma unroll
  for (int k = 0; k < 8; ++k) {
    const half2v ak2 = bch2((uint32_t)__shfl((int)adu, gb | k));
    const uint2 vv = *reinterpret_cast<const uint2*>(vwin + k * 32 + d0);
    o01 += ak2 * bch2(vv.x);
    o23 += ak2 * bch2(vv.y);
  }

  // ---- LePE: depthwise 3x3 on v (zero-pad SAME); taps are contiguous blocks ----
  const int hq = h0 + ((half == 0) ? qr : 0);
  const int wq = w0 + ((half == 0) ? 0 : qr);
  const unsigned short* vplane = qkvp + 33554432;
  const unsigned short* wl = wlep + half * 2304 + n * 32 + d0;
  half2v l01 = {0, 0}, l23 = {0, 0};
  #pragma unroll
  for (int dy = -1; dy <= 1; ++dy) {
    #pragma unroll
    for (int dx = -1; dx <= 1; ++dx) {
      const int hh = hq + dy, ww = wq + dx;
      uint2 vv; vv.x = 0u; vv.y = 0u;
      if ((unsigned)hh < 64u && (unsigned)ww < 64u)
        vv = *reinterpret_cast<const uint2*>(vplane + qkv_idx(half, b, n, hh, ww) + d0);
      const uint2 wt = *reinterpret_cast<const uint2*>(wl + ((dy + 1) * 3 + dx + 1) * 256);
      l01 += bch2(wt.x) * bch2(vv.x);
      l23 += bch2(wt.y) * bch2(vv.y);
    }
  }

  // ---- store token-major for GEMM2 ----
  const int m = b * 4096 + hq * 64 + wq;
  const int chan0 = half * 256 + n * 32;
  const half2v r01 = o01 + l01;
  const half2v r23 = o23 + l23;
  uint2 r;
  r.x = __builtin_bit_cast(uint32_t, r01);
  r.y = __builtin_bit_cast(uint32_t, r23);
  *reinterpret_cast<uint2*>(outp + (size_t)m * 512 + chan0 + d0) = r;
}

// ---------- launch ----------
extern "C" void kernel_launch(void* const* d_in, const int* in_sizes, int n_in,
                              void* d_out, int out_size, void* d_ws, size_t ws_size,
                              hipStream_t stream) {
  const float* x      = (const float*)d_in[0];   // (8, 4096, 512)
  const float* w_qkv  = (const float*)d_in[1];   // (1536, 512)
  const float* w_proj = (const float*)d_in[2];   // (512, 512)
  const float* b_proj = (const float*)d_in[3];   // (512,)
  const float* lepe_h = (const float*)d_in[4];   // (3,3,1,256)
  const float* lepe_v = (const float*)d_in[5];   // (3,3,1,256)
  float* out = (float*)d_out;                    // (8, 4096, 512) f32

  char* ws = (char*)d_ws;
  unsigned short* qkv_p   = (unsigned short*)ws;                 // 96MB: q|k|v window-major
  unsigned short* xh      = (unsigned short*)(ws + 100663296);   // 32MB: x f16; reused as attn_out
  unsigned short* wqkv_h  = (unsigned short*)(ws + 134217728);   // 1536*512 f16
  unsigned short* wproj_h = (unsigned short*)(ws + 135790592);   // 512*512 f16
  unsigned short* wlep_h  = (unsigned short*)(ws + 136314880);   // 2*9*256 f16

  // casts
  cvt_f32_f16<<<16384, 256, 0, stream>>>(x, xh, 4194304);
  cvt_f32_f16<<<768,   256, 0, stream>>>(w_qkv, wqkv_h, 196608);
  cvt_f32_f16<<<256,   256, 0, stream>>>(w_proj, wproj_h, 65536);
  cvt_f32_f16<<<3,     256, 0, stream>>>(lepe_h, wlep_h, 576);
  cvt_f32_f16<<<3,     256, 0, stream>>>(lepe_v, wlep_h + 2304, 576);

  // qkv = x @ w_qkv^T -> window-major f16 regions
  gemm_bt<1><<<dim3(256, 12), 256, 0, stream>>>(
      xh, wqkv_h, qkv_p, nullptr, nullptr, 32768, 1536, 512);

  // stripe attention + LePE -> attn_out token-major (xh region; xh dead)
  attn_lepe<<<16384, 256, 0, stream>>>(qkv_p, wlep_h, xh);

  // out = attn_out @ w_proj^T + b_proj -> f32
  gemm_bt<0><<<dim3(256, 4), 256, 0, stream>>>(
      xh, wproj_h, nullptr, out, b_proj, 32768, 512, 512);
}

// Round 7
// 208.007 us; speedup vs baseline: 1.1422x; 1.1422x over previous
//
#include <hip/hip_runtime.h>
#include <hip/hip_bf16.h>
#include <stdint.h>

// ---------- types ----------
typedef _Float16 half2v __attribute__((ext_vector_type(2)));
typedef _Float16 half8v __attribute__((ext_vector_type(8)));
typedef uint32_t u32x4  __attribute__((ext_vector_type(4)));
typedef float    f32x4  __attribute__((ext_vector_type(4)));

__device__ __forceinline__ unsigned short f2h(float f) {
  _Float16 h = (_Float16)f;
  return __builtin_bit_cast(unsigned short, h);
}
__device__ __forceinline__ half2v bch2(uint32_t u) {
  return __builtin_bit_cast(half2v, u);
}
__device__ __forceinline__ uint32_t pkrtz_u32(float a, float b) {
  return __builtin_bit_cast(uint32_t, __builtin_amdgcn_cvt_pkrtz(a, b));
}

// Window-major qkv layout. Element index (channel 0 of head n) for pixel (h,w),
// within one tensor's 32MB region (16M f16 elems; includes the half offset).
//  half 0 (horizontal stripes): [b][n][s=h>>3][w][qr=h&7][cc]
//  half 1 (vertical stripes):   [b][n][h][s=w>>3][qr=w&7][cc]  (s*256+qr*32 == w*32)
__device__ __forceinline__ int qkv_idx(int half, int b, int n, int h, int w) {
  int idx = half * 8388608 + (b * 8 + n) * 131072;
  idx += (half == 0) ? ((h >> 3) * 16384 + w * 256 + (h & 7) * 32)
                     : (h * 2048 + w * 32);
  return idx;
}

// async global->LDS, 16 bytes per lane. lbase must be wave-uniform.
#define GLOAD_LDS16(gsrc, lbase)                                          \
  __builtin_amdgcn_global_load_lds(                                       \
      (const __attribute__((address_space(1))) uint32_t*)(gsrc),          \
      (__attribute__((address_space(3))) uint32_t*)(lbase), 16, 0, 0)

// ---------- f32 -> f16 conversion (4 elems/thread) ----------
__global__ __launch_bounds__(256) void cvt_f32_f16(const float* __restrict__ in,
                                                   unsigned short* __restrict__ out,
                                                   int n4) {
  int i = blockIdx.x * 256 + threadIdx.x;
  if (i >= n4) return;
  float4 f = reinterpret_cast<const float4*>(in)[i];
  ushort4 u;
  u.x = f2h(f.x); u.y = f2h(f.y); u.z = f2h(f.z); u.w = f2h(f.w);
  reinterpret_cast<ushort4*>(out)[i] = u;
}

// ---------- f16 GEMM, C[m,n] = sum_k A[m,k]*B[n,k]  (A: MxK, B: NxK row-major)
// 128x128 tile, 4 waves (2x2), each wave 64x64 = 4x4 frags, MFMA 16x16x32 f16.
// T4 pipeline: double-buffered LDS (32KB), stage tile t+1 before compute of
// tile t, COUNTED s_waitcnt vmcnt(4) (never 0 in the loop) + raw s_barrier —
// tile t+1's loads stay in flight across both barriers and the MFMA phase.
// Race analysis: tile-t visibility = own vmcnt(4) + barrier; buffer overwrite
// protected by end-of-iter barrier (all ds_reads MFMA-consumed before it).
// Operand-swapped MFMA epilogue (lane holds 4 contiguous n at one m).
// LDS k-slot XOR swizzle (pre-swizzled global source; linear gload_lds dest).
// MODE 0: f32 out + bias, token-major (GEMM2).
// MODE 1: f16 out scattered to window-major qkv regions (GEMM1, N=1536).
template<int MODE>
__global__ __launch_bounds__(256) void gemm_bt(
    const unsigned short* __restrict__ A,
    const unsigned short* __restrict__ B,
    unsigned short* __restrict__ Cq,
    float* __restrict__ Cf,
    const float* __restrict__ bias,
    int M, int N, int K)
{
  __shared__ unsigned short As[2][128 * 32];
  __shared__ unsigned short Bs[2][128 * 32];
  const int tid  = threadIdx.x;
  const int m0   = blockIdx.x * 128;
  const int n0   = blockIdx.y * 128;
  const int wave = tid >> 6, lane = tid & 63;
  const int wr = wave >> 1, wc = wave & 1;
  const int sr = tid >> 2;                                // staging row 0..63
  const int sc = ((tid & 3) ^ ((tid >> 3) & 3)) * 8;      // pre-swizzled k-chunk
  const size_t aBase0 = (size_t)(m0 + sr) * K + sc;
  const size_t aBase1 = (size_t)(m0 + 64 + sr) * K + sc;
  const size_t bBase0 = (size_t)(n0 + sr) * K + sc;
  const size_t bBase1 = (size_t)(n0 + 64 + sr) * K + sc;
  // per-thread LDS dest is linear tid*16B within each buffer; wave-uniform base
  char* ldsA = (char*)(&As[0][0]) + (tid & ~63) * 16;
  char* ldsB = (char*)(&Bs[0][0]) + (tid & ~63) * 16;

  // stage tile `t` slice into buffer `bsel`
#define STAGE_TILE(bsel, kofs)                                  \
  do {                                                          \
    GLOAD_LDS16(A + aBase0 + (kofs), ldsA + (bsel) * 8192);     \
    GLOAD_LDS16(A + aBase1 + (kofs), ldsA + (bsel) * 8192 + 4096); \
    GLOAD_LDS16(B + bBase0 + (kofs), ldsB + (bsel) * 8192);     \
    GLOAD_LDS16(B + bBase1 + (kofs), ldsB + (bsel) * 8192 + 4096); \
  } while (0)

  // prologue: stage tile 0 into buf0; acc-init overlaps the loads
  STAGE_TILE(0, 0);

  f32x4 acc[4][4];
  const f32x4 zero = {0.f, 0.f, 0.f, 0.f};
  #pragma unroll
  for (int i = 0; i < 4; ++i)
    #pragma unroll
    for (int j = 0; j < 4; ++j) acc[i][j] = zero;

  const int lr   = lane & 15;
  const int slot = (lane >> 4) ^ ((lr >> 1) & 3);   // swizzled k-slot (elems/8)

  auto compute = [&](const unsigned short* Asb, const unsigned short* Bsb) {
    half8v af[4], bfr[4];
    #pragma unroll
    for (int i = 0; i < 4; ++i)
      af[i] = *reinterpret_cast<const half8v*>(Asb + (wr * 64 + i * 16 + lr) * 32 + slot * 8);
    #pragma unroll
    for (int j = 0; j < 4; ++j)
      bfr[j] = *reinterpret_cast<const half8v*>(Bsb + (wc * 64 + j * 16 + lr) * 32 + slot * 8);
    __builtin_amdgcn_s_setprio(1);
    #pragma unroll
    for (int i = 0; i < 4; ++i)
      #pragma unroll
      for (int j = 0; j < 4; ++j)
        acc[i][j] = __builtin_amdgcn_mfma_f32_16x16x32_f16(bfr[j], af[i], acc[i][j], 0, 0, 0);
    __builtin_amdgcn_s_setprio(0);
  };

  const int nt = K >> 5;   // K/32 tiles
  for (int t = 0; t < nt - 1; ++t) {
    STAGE_TILE((t + 1) & 1, (t + 1) * 32);          // issue next-tile loads
    asm volatile("s_waitcnt vmcnt(4)" ::: "memory"); // tile t's 4 loads done;
                                                     // tile t+1's stay in flight
    __builtin_amdgcn_s_barrier();                    // tile t visible to all
    __builtin_amdgcn_sched_barrier(0);
    compute(&As[t & 1][0], &Bs[t & 1][0]);
    __builtin_amdgcn_s_barrier();                    // all done reading buf[t&1]
    __builtin_amdgcn_sched_barrier(0);
  }
  // epilogue tile: drain remaining loads
  asm volatile("s_waitcnt vmcnt(0)" ::: "memory");
  __builtin_amdgcn_s_barrier();
  __builtin_amdgcn_sched_barrier(0);
  compute(&As[(nt - 1) & 1][0], &Bs[(nt - 1) & 1][0]);
#undef STAGE_TILE

  // D layout (operand-swapped): row (n-dim) = (lane>>4)*4 + t, col (m-dim) = lane&15
  const int cr = (lane >> 4) * 4;   // channel offset (4 contiguous)
  const int cc = lane & 15;         // token offset

  if constexpr (MODE == 0) {
    #pragma unroll
    for (int j = 0; j < 4; ++j) {
      const int n = n0 + wc * 64 + j * 16 + cr;
      const float4 b4 = *reinterpret_cast<const float4*>(bias + n);
      #pragma unroll
      for (int i = 0; i < 4; ++i) {
        const int m = m0 + wr * 64 + i * 16 + cc;
        float4 r;
        r.x = acc[i][j][0] + b4.x;
        r.y = acc[i][j][1] + b4.y;
        r.z = acc[i][j][2] + b4.z;
        r.w = acc[i][j][3] + b4.w;
        *reinterpret_cast<float4*>(Cf + (size_t)m * N + n) = r;
      }
    }
  } else {
    const int mb   = m0 + wr * 64;    // token base (wave-uniform)
    const int btok = mb >> 12;
    const int htok = (mb >> 6) & 63;
    #pragma unroll
    for (int j = 0; j < 4; ++j) {
      const int nb    = n0 + wc * 64 + j * 16 + cr;  // 4 contiguous channels
      const int tq    = nb >> 9;                     // 0=q 1=k 2=v
      const int halfc = (nb >> 8) & 1;
      const int nn    = (nb & 255) >> 5;
      const int ch4   = nb & 31;
      int base = tq * 16777216 + halfc * 8388608 + (btok * 8 + nn) * 131072 + ch4;
      base += halfc ? (htok * 2048) : ((htok >> 3) * 16384 + (htok & 7) * 32);
      const int wstride = halfc ? 32 : 256;
      #pragma unroll
      for (int i = 0; i < 4; ++i) {
        const int wpix = i * 16 + cc;
        uint2 r;
        r.x = pkrtz_u32(acc[i][j][0], acc[i][j][1]);
        r.y = pkrtz_u32(acc[i][j][2], acc[i][j][3]);
        *reinterpret_cast<uint2*>(Cq + base + wpix * wstride) = r;
      }
    }
  }
}

// ---------- stripe attention + LePE on window-major qkv ----------
// qkvp: q region (32MB) | k region (32MB) | v region (32MB), f16, window-major.
// wlep: f16 LePE weights [half][tap(9)][256].
// outp: token-major 32768 x 512 f16.
__global__ __launch_bounds__(256) void attn_lepe(
    const unsigned short* __restrict__ qkvp,
    const unsigned short* __restrict__ wlep,
    unsigned short* __restrict__ outp)
{
  const int gw   = (int)((blockIdx.x * 256 + threadIdx.x) >> 6);
  const int lane = threadIdx.x & 63;
  const int half = gw >> 15;
  const int id   = gw & 32767;
  const int b    = id >> 12;
  const int n    = (id >> 9) & 7;
  int h0, w0;
  if (half == 0) { const int s = (id >> 6) & 7; h0 = s * 8; w0 = id & 63; }
  else           { const int s = id & 7; h0 = (id >> 3) & 63; w0 = s * 8; }
  const int winbase = qkv_idx(half, b, n, h0, w0);
  const unsigned short* qwin = qkvp + winbase;
  const unsigned short* kwin = qkvp + 16777216 + winbase;
  const unsigned short* vwin = qkvp + 33554432 + winbase;

  // ---- QK^T: lane (qr, kr); window rows are 32-elem contiguous ----
  const int qr = lane >> 3, kr = lane & 7;
  const unsigned short* qp = qwin + qr * 32;
  const unsigned short* kp = kwin + kr * 32;
  float s_val = 0.f;
  #pragma unroll
  for (int c = 0; c < 4; ++c) {
    u32x4 qv = *reinterpret_cast<const u32x4*>(qp + c * 8);
    u32x4 kv = *reinterpret_cast<const u32x4*>(kp + c * 8);
    #pragma unroll
    for (int e = 0; e < 4; ++e)
      s_val = __builtin_amdgcn_fdot2(bch2(qv[e]), bch2(kv[e]), s_val, false);
  }
  s_val *= 0.17677669529663687f;  // 1/sqrt(32)

  // ---- softmax over k within each 8-lane group (|s| small: no max pass) ----
  float p = __expf(s_val);
  float den = p;
  den += __shfl_xor(den, 1);
  den += __shfl_xor(den, 2);
  den += __shfl_xor(den, 4);
  const float a = p * __builtin_amdgcn_rcpf(den);
  const _Float16 ah = (_Float16)a;
  half2v ad = {ah, ah};
  const uint32_t adu = __builtin_bit_cast(uint32_t, ad);

  // ---- PV: lane (qr, d0); v row k is one 64B line for the whole wave ----
  const int d0 = (lane & 7) * 4;
  const int gb = lane & 56;
  half2v o01 = {0, 0}, o23 = {0, 0};
  #pragma unroll
  for (int k = 0; k < 8; ++k) {
    const half2v ak2 = bch2((uint32_t)__shfl((int)adu, gb | k));
    const uint2 vv = *reinterpret_cast<const uint2*>(vwin + k * 32 + d0);
    o01 += ak2 * bch2(vv.x);
    o23 += ak2 * bch2(vv.y);
  }

  // ---- LePE: depthwise 3x3 on v (zero-pad SAME); taps are contiguous blocks ----
  const int hq = h0 + ((half == 0) ? qr : 0);
  const int wq = w0 + ((half == 0) ? 0 : qr);
  const unsigned short* vplane = qkvp + 33554432;
  const unsigned short* wl = wlep + half * 2304 + n * 32 + d0;
  half2v l01 = {0, 0}, l23 = {0, 0};
  #pragma unroll
  for (int dy = -1; dy <= 1; ++dy) {
    #pragma unroll
    for (int dx = -1; dx <= 1; ++dx) {
      const int hh = hq + dy, ww = wq + dx;
      uint2 vv; vv.x = 0u; vv.y = 0u;
      if ((unsigned)hh < 64u && (unsigned)ww < 64u)
        vv = *reinterpret_cast<const uint2*>(vplane + qkv_idx(half, b, n, hh, ww) + d0);
      const uint2 wt = *reinterpret_cast<const uint2*>(wl + ((dy + 1) * 3 + dx + 1) * 256);
      l01 += bch2(wt.x) * bch2(vv.x);
      l23 += bch2(wt.y) * bch2(vv.y);
    }
  }

  // ---- store token-major for GEMM2 ----
  const int m = b * 4096 + hq * 64 + wq;
  const int chan0 = half * 256 + n * 32;
  const half2v r01 = o01 + l01;
  const half2v r23 = o23 + l23;
  uint2 r;
  r.x = __builtin_bit_cast(uint32_t, r01);
  r.y = __builtin_bit_cast(uint32_t, r23);
  *reinterpret_cast<uint2*>(outp + (size_t)m * 512 + chan0 + d0) = r;
}

// ---------- launch ----------
extern "C" void kernel_launch(void* const* d_in, const int* in_sizes, int n_in,
                              void* d_out, int out_size, void* d_ws, size_t ws_size,
                              hipStream_t stream) {
  const float* x      = (const float*)d_in[0];   // (8, 4096, 512)
  const float* w_qkv  = (const float*)d_in[1];   // (1536, 512)
  const float* w_proj = (const float*)d_in[2];   // (512, 512)
  const float* b_proj = (const float*)d_in[3];   // (512,)
  const float* lepe_h = (const float*)d_in[4];   // (3,3,1,256)
  const float* lepe_v = (const float*)d_in[5];   // (3,3,1,256)
  float* out = (float*)d_out;                    // (8, 4096, 512) f32

  char* ws = (char*)d_ws;
  unsigned short* qkv_p   = (unsigned short*)ws;                 // 96MB: q|k|v window-major
  unsigned short* xh      = (unsigned short*)(ws + 100663296);   // 32MB: x f16; reused as attn_out
  unsigned short* wqkv_h  = (unsigned short*)(ws + 134217728);   // 1536*512 f16
  unsigned short* wproj_h = (unsigned short*)(ws + 135790592);   // 512*512 f16
  unsigned short* wlep_h  = (unsigned short*)(ws + 136314880);   // 2*9*256 f16

  // casts
  cvt_f32_f16<<<16384, 256, 0, stream>>>(x, xh, 4194304);
  cvt_f32_f16<<<768,   256, 0, stream>>>(w_qkv, wqkv_h, 196608);
  cvt_f32_f16<<<256,   256, 0, stream>>>(w_proj, wproj_h, 65536);
  cvt_f32_f16<<<3,     256, 0, stream>>>(lepe_h, wlep_h, 576);
  cvt_f32_f16<<<3,     256, 0, stream>>>(lepe_v, wlep_h + 2304, 576);

  // qkv = x @ w_qkv^T -> window-major f16 regions
  gemm_bt<1><<<dim3(256, 12), 256, 0, stream>>>(
      xh, wqkv_h, qkv_p, nullptr, nullptr, 32768, 1536, 512);

  // stripe attention + LePE -> attn_out token-major (xh region; xh dead)
  attn_lepe<<<16384, 256, 0, stream>>>(qkv_p, wlep_h, xh);

  // out = attn_out @ w_proj^T + b_proj -> f32
  gemm_bt<0><<<dim3(256, 4), 256, 0, stream>>>(
      xh, wproj_h, nullptr, out, b_proj, 32768, 512, 512);
}

// Round 8
// 194.272 us; speedup vs baseline: 1.2229x; 1.0707x over previous
//
#include <hip/hip_runtime.h>
#include <hip/hip_bf16.h>
#include <stdint.h>

// ---------- types ----------
typedef _Float16 half2v __attribute__((ext_vector_type(2)));
typedef _Float16 half8v __attribute__((ext_vector_type(8)));
typedef uint32_t u32x4  __attribute__((ext_vector_type(4)));
typedef float    f32x4  __attribute__((ext_vector_type(4)));

__device__ __forceinline__ unsigned short f2h(float f) {
  _Float16 h = (_Float16)f;
  return __builtin_bit_cast(unsigned short, h);
}
__device__ __forceinline__ half2v bch2(uint32_t u) {
  return __builtin_bit_cast(half2v, u);
}
__device__ __forceinline__ uint32_t pkrtz_u32(float a, float b) {
  return __builtin_bit_cast(uint32_t, __builtin_amdgcn_cvt_pkrtz(a, b));
}

// Window-major qkv layout. Element index (channel 0 of head n) for pixel (h,w),
// within one tensor's 32MB region (16M f16 elems; includes the half offset).
//  half 0 (horizontal stripes): [b][n][s=h>>3][w][qr=h&7][cc]
//  half 1 (vertical stripes):   [b][n][h][s=w>>3][qr=w&7][cc]  (s*256+qr*32 == w*32)
__device__ __forceinline__ int qkv_idx(int half, int b, int n, int h, int w) {
  int idx = half * 8388608 + (b * 8 + n) * 131072;
  idx += (half == 0) ? ((h >> 3) * 16384 + w * 256 + (h & 7) * 32)
                     : (h * 2048 + w * 32);
  return idx;
}

// async global->LDS, 16 bytes per lane. lbase must be wave-uniform.
#define GLOAD_LDS16(gsrc, lbase)                                          \
  __builtin_amdgcn_global_load_lds(                                       \
      (const __attribute__((address_space(1))) uint32_t*)(gsrc),          \
      (__attribute__((address_space(3))) uint32_t*)(lbase), 16, 0, 0)

// ---------- f32 -> f16 conversion (4 elems/thread) ----------
__global__ __launch_bounds__(256) void cvt_f32_f16(const float* __restrict__ in,
                                                   unsigned short* __restrict__ out,
                                                   int n4) {
  int i = blockIdx.x * 256 + threadIdx.x;
  if (i >= n4) return;
  float4 f = reinterpret_cast<const float4*>(in)[i];
  ushort4 u;
  u.x = f2h(f.x); u.y = f2h(f.y); u.z = f2h(f.z); u.w = f2h(f.w);
  reinterpret_cast<ushort4*>(out)[i] = u;
}

// ---------- f16 GEMM, C[m,n] = sum_k A[m,k]*B[n,k]  (A: MxK, B: NxK row-major)
// 128x128 tile, 4 waves (2x2), each wave 64x64 = 4x4 frags, MFMA 16x16x32 f16.
// Grid: x = n-tile (FAST -> concurrent blocks share A-panel in L2), y = m-tile.
// T4 pipeline: double-buffered LDS, stage tile t+1 before compute of tile t,
// counted s_waitcnt vmcnt(4) (never 0 in loop) + raw s_barrier.
// Operand-swapped MFMA epilogue (lane holds 4 contiguous n at one m).
// LDS k-slot XOR swizzle (pre-swizzled global source; linear gload_lds dest).
// MODE 0: f32 out + bias, token-major (GEMM2).
// MODE 1: f16 out scattered to window-major qkv regions (GEMM1, N=1536).
template<int MODE>
__global__ __launch_bounds__(256) void gemm_bt(
    const unsigned short* __restrict__ A,
    const unsigned short* __restrict__ B,
    unsigned short* __restrict__ Cq,
    float* __restrict__ Cf,
    const float* __restrict__ bias,
    int M, int N, int K)
{
  __shared__ unsigned short As[2][128 * 32];
  __shared__ unsigned short Bs[2][128 * 32];
  const int tid  = threadIdx.x;
  const int m0   = blockIdx.y * 128;
  const int n0   = blockIdx.x * 128;
  const int wave = tid >> 6, lane = tid & 63;
  const int wr = wave >> 1, wc = wave & 1;
  const int sr = tid >> 2;                                // staging row 0..63
  const int sc = ((tid & 3) ^ ((tid >> 3) & 3)) * 8;      // pre-swizzled k-chunk
  const size_t aBase0 = (size_t)(m0 + sr) * K + sc;
  const size_t aBase1 = (size_t)(m0 + 64 + sr) * K + sc;
  const size_t bBase0 = (size_t)(n0 + sr) * K + sc;
  const size_t bBase1 = (size_t)(n0 + 64 + sr) * K + sc;
  // per-thread LDS dest is linear tid*16B within each buffer; wave-uniform base
  char* ldsA = (char*)(&As[0][0]) + (tid & ~63) * 16;
  char* ldsB = (char*)(&Bs[0][0]) + (tid & ~63) * 16;

#define STAGE_TILE(bsel, kofs)                                  \
  do {                                                          \
    GLOAD_LDS16(A + aBase0 + (kofs), ldsA + (bsel) * 8192);     \
    GLOAD_LDS16(A + aBase1 + (kofs), ldsA + (bsel) * 8192 + 4096); \
    GLOAD_LDS16(B + bBase0 + (kofs), ldsB + (bsel) * 8192);     \
    GLOAD_LDS16(B + bBase1 + (kofs), ldsB + (bsel) * 8192 + 4096); \
  } while (0)

  // prologue: stage tile 0 into buf0; acc-init overlaps the loads
  STAGE_TILE(0, 0);

  f32x4 acc[4][4];
  const f32x4 zero = {0.f, 0.f, 0.f, 0.f};
  #pragma unroll
  for (int i = 0; i < 4; ++i)
    #pragma unroll
    for (int j = 0; j < 4; ++j) acc[i][j] = zero;

  const int lr   = lane & 15;
  const int slot = (lane >> 4) ^ ((lr >> 1) & 3);   // swizzled k-slot (elems/8)

  auto compute = [&](const unsigned short* Asb, const unsigned short* Bsb) {
    half8v af[4], bfr[4];
    #pragma unroll
    for (int i = 0; i < 4; ++i)
      af[i] = *reinterpret_cast<const half8v*>(Asb + (wr * 64 + i * 16 + lr) * 32 + slot * 8);
    #pragma unroll
    for (int j = 0; j < 4; ++j)
      bfr[j] = *reinterpret_cast<const half8v*>(Bsb + (wc * 64 + j * 16 + lr) * 32 + slot * 8);
    __builtin_amdgcn_s_setprio(1);
    #pragma unroll
    for (int i = 0; i < 4; ++i)
      #pragma unroll
      for (int j = 0; j < 4; ++j)
        acc[i][j] = __builtin_amdgcn_mfma_f32_16x16x32_f16(bfr[j], af[i], acc[i][j], 0, 0, 0);
    __builtin_amdgcn_s_setprio(0);
  };

  const int nt = K >> 5;   // K/32 tiles
  for (int t = 0; t < nt - 1; ++t) {
    STAGE_TILE((t + 1) & 1, (t + 1) * 32);          // issue next-tile loads
    asm volatile("s_waitcnt vmcnt(4)" ::: "memory"); // tile t's 4 loads done;
                                                     // tile t+1's stay in flight
    __builtin_amdgcn_s_barrier();                    // tile t visible to all
    __builtin_amdgcn_sched_barrier(0);
    compute(&As[t & 1][0], &Bs[t & 1][0]);
    __builtin_amdgcn_s_barrier();                    // all done reading buf[t&1]
    __builtin_amdgcn_sched_barrier(0);
  }
  // epilogue tile: drain remaining loads
  asm volatile("s_waitcnt vmcnt(0)" ::: "memory");
  __builtin_amdgcn_s_barrier();
  __builtin_amdgcn_sched_barrier(0);
  compute(&As[(nt - 1) & 1][0], &Bs[(nt - 1) & 1][0]);
#undef STAGE_TILE

  // D layout (operand-swapped): row (n-dim) = (lane>>4)*4 + t, col (m-dim) = lane&15
  const int cr = (lane >> 4) * 4;   // channel offset (4 contiguous)
  const int cc = lane & 15;         // token offset

  if constexpr (MODE == 0) {
    #pragma unroll
    for (int j = 0; j < 4; ++j) {
      const int n = n0 + wc * 64 + j * 16 + cr;
      const float4 b4 = *reinterpret_cast<const float4*>(bias + n);
      #pragma unroll
      for (int i = 0; i < 4; ++i) {
        const int m = m0 + wr * 64 + i * 16 + cc;
        float4 r;
        r.x = acc[i][j][0] + b4.x;
        r.y = acc[i][j][1] + b4.y;
        r.z = acc[i][j][2] + b4.z;
        r.w = acc[i][j][3] + b4.w;
        *reinterpret_cast<float4*>(Cf + (size_t)m * N + n) = r;
      }
    }
  } else {
    const int mb   = m0 + wr * 64;    // token base (wave-uniform)
    const int btok = mb >> 12;
    const int htok = (mb >> 6) & 63;
    #pragma unroll
    for (int j = 0; j < 4; ++j) {
      const int nb    = n0 + wc * 64 + j * 16 + cr;  // 4 contiguous channels
      const int tq    = nb >> 9;                     // 0=q 1=k 2=v
      const int halfc = (nb >> 8) & 1;
      const int nn    = (nb & 255) >> 5;
      const int ch4   = nb & 31;
      int base = tq * 16777216 + halfc * 8388608 + (btok * 8 + nn) * 131072 + ch4;
      base += halfc ? (htok * 2048) : ((htok >> 3) * 16384 + (htok & 7) * 32);
      const int wstride = halfc ? 32 : 256;
      #pragma unroll
      for (int i = 0; i < 4; ++i) {
        const int wpix = i * 16 + cc;
        uint2 r;
        r.x = pkrtz_u32(acc[i][j][0], acc[i][j][1]);
        r.y = pkrtz_u32(acc[i][j][2], acc[i][j][3]);
        *reinterpret_cast<uint2*>(Cq + base + wpix * wstride) = r;
      }
    }
  }
}

// ---------- stripe attention + LePE, TWO windows per wave ----------
// qkvp: q (32MB) | k (32MB) | v (32MB), f16, window-major.
// wlep: f16 LePE weights [half][tap(9)][256].
// outp: token-major 32768 x 512 f16.
// Pairing: half 0 pairs adjacent columns (w, w+1) of one h-stripe;
//          half 1 pairs adjacent rows (h, h+1) of one w-stripe.
// Phase QK: lane=(qr,kr) computes both windows' logits (packed f16x2 weight).
// Phase PV/LePE/store: lane=(qr2, win, dgrp) with 16B vectors (8 ch).
__global__ __launch_bounds__(256) void attn_lepe(
    const unsigned short* __restrict__ qkvp,
    const unsigned short* __restrict__ wlep,
    unsigned short* __restrict__ outp)
{
  const int gw   = (int)((blockIdx.x * 256 + threadIdx.x) >> 6);  // pair index
  const int lane = threadIdx.x & 63;
  const int half = gw >> 14;
  const int id   = gw & 16383;
  const int b    = id >> 11;
  const int n    = (id >> 8) & 7;
  int h0, w0;
  if (half == 0) { h0 = ((id >> 5) & 7) * 8; w0 = (id & 31) * 2; }
  else           { h0 = ((id >> 3) & 31) * 2; w0 = (id & 7) * 8; }
  const int baseA = qkv_idx(half, b, n, h0, w0);
  const int dWin  = (half == 0) ? 256 : 2048;   // adjacent-window offset
  const int baseB = baseA + dWin;

  // ---- QK^T for both windows: lane = (qr, kr) ----
  const int qr = lane >> 3, kr = lane & 7;
  const unsigned short* qA = qkvp + baseA + qr * 32;
  const unsigned short* kA = qkvp + 16777216 + baseA + kr * 32;
  float sA = 0.f, sB = 0.f;
  #pragma unroll
  for (int c = 0; c < 4; ++c) {
    const u32x4 qa = *reinterpret_cast<const u32x4*>(qA + c * 8);
    const u32x4 ka = *reinterpret_cast<const u32x4*>(kA + c * 8);
    const u32x4 qb = *reinterpret_cast<const u32x4*>(qA + dWin + c * 8);
    const u32x4 kb = *reinterpret_cast<const u32x4*>(kA + dWin + c * 8);
    #pragma unroll
    for (int e = 0; e < 4; ++e) {
      sA = __builtin_amdgcn_fdot2(bch2(qa[e]), bch2(ka[e]), sA, false);
      sB = __builtin_amdgcn_fdot2(bch2(qb[e]), bch2(kb[e]), sB, false);
    }
  }
  const float scl = 0.17677669529663687f;  // 1/sqrt(32)
  const float pA = __expf(sA * scl);
  const float pB = __expf(sB * scl);
  float denA = pA, denB = pB;
  denA += __shfl_xor(denA, 1); denA += __shfl_xor(denA, 2); denA += __shfl_xor(denA, 4);
  denB += __shfl_xor(denB, 1); denB += __shfl_xor(denB, 2); denB += __shfl_xor(denB, 4);
  const float aAv = pA * __builtin_amdgcn_rcpf(denA);
  const float aBv = pB * __builtin_amdgcn_rcpf(denB);
  const uint32_t adu = pkrtz_u32(aAv, aBv);   // lo = winA, hi = winB

  // ---- PV: lane = (qr2, win, dgrp); 16B vectors over 8 channels ----
  const int dgrp = lane & 3;
  const int win  = (lane >> 2) & 1;
  const int qr2  = lane >> 3;
  const int d0   = dgrp * 8;
  const int mybase = win ? baseB : baseA;
  const unsigned short* vwin = qkvp + 33554432 + mybase;

  half2v o01 = {0,0}, o23 = {0,0}, o45 = {0,0}, o67 = {0,0};
  #pragma unroll
  for (int k = 0; k < 8; ++k) {
    const uint32_t pairw = (uint32_t)__shfl((int)adu, qr2 * 8 + k);
    const half2v ph = bch2(pairw);
    const _Float16 av = win ? ph.y : ph.x;
    const half2v ak2 = {av, av};
    const u32x4 vv = *reinterpret_cast<const u32x4*>(vwin + k * 32 + d0);
    o01 += ak2 * bch2(vv[0]);
    o23 += ak2 * bch2(vv[1]);
    o45 += ak2 * bch2(vv[2]);
    o67 += ak2 * bch2(vv[3]);
  }

  // ---- LePE: depthwise 3x3 on v (zero-pad SAME) at this lane's pixel ----
  const int hq = (half == 0) ? (h0 + qr2) : (h0 + win);
  const int wq = (half == 0) ? (w0 + win) : (w0 + qr2);
  const unsigned short* vplane = qkvp + 33554432;
  const unsigned short* wl = wlep + half * 2304 + n * 32 + d0;
  half2v l01 = {0,0}, l23 = {0,0}, l45 = {0,0}, l67 = {0,0};
  #pragma unroll
  for (int dy = -1; dy <= 1; ++dy) {
    #pragma unroll
    for (int dx = -1; dx <= 1; ++dx) {
      const int hh = hq + dy, ww = wq + dx;
      u32x4 vv = {0u, 0u, 0u, 0u};
      if ((unsigned)hh < 64u && (unsigned)ww < 64u)
        vv = *reinterpret_cast<const u32x4*>(vplane + qkv_idx(half, b, n, hh, ww) + d0);
      const u32x4 wt = *reinterpret_cast<const u32x4*>(wl + ((dy + 1) * 3 + dx + 1) * 256);
      l01 += bch2(wt[0]) * bch2(vv[0]);
      l23 += bch2(wt[1]) * bch2(vv[1]);
      l45 += bch2(wt[2]) * bch2(vv[2]);
      l67 += bch2(wt[3]) * bch2(vv[3]);
    }
  }

  // ---- store token-major for GEMM2 (16B per lane) ----
  const int m = b * 4096 + hq * 64 + wq;
  const int chan0 = half * 256 + n * 32;
  u32x4 r;
  r[0] = __builtin_bit_cast(uint32_t, (half2v)(o01 + l01));
  r[1] = __builtin_bit_cast(uint32_t, (half2v)(o23 + l23));
  r[2] = __builtin_bit_cast(uint32_t, (half2v)(o45 + l45));
  r[3] = __builtin_bit_cast(uint32_t, (half2v)(o67 + l67));
  *reinterpret_cast<u32x4*>(outp + (size_t)m * 512 + chan0 + d0) = r;
}

// ---------- launch ----------
extern "C" void kernel_launch(void* const* d_in, const int* in_sizes, int n_in,
                              void* d_out, int out_size, void* d_ws, size_t ws_size,
                              hipStream_t stream) {
  const float* x      = (const float*)d_in[0];   // (8, 4096, 512)
  const float* w_qkv  = (const float*)d_in[1];   // (1536, 512)
  const float* w_proj = (const float*)d_in[2];   // (512, 512)
  const float* b_proj = (const float*)d_in[3];   // (512,)
  const float* lepe_h = (const float*)d_in[4];   // (3,3,1,256)
  const float* lepe_v = (const float*)d_in[5];   // (3,3,1,256)
  float* out = (float*)d_out;                    // (8, 4096, 512) f32

  char* ws = (char*)d_ws;
  unsigned short* qkv_p   = (unsigned short*)ws;                 // 96MB: q|k|v window-major
  unsigned short* xh      = (unsigned short*)(ws + 100663296);   // 32MB: x f16; reused as attn_out
  unsigned short* wqkv_h  = (unsigned short*)(ws + 134217728);   // 1536*512 f16
  unsigned short* wproj_h = (unsigned short*)(ws + 135790592);   // 512*512 f16
  unsigned short* wlep_h  = (unsigned short*)(ws + 136314880);   // 2*9*256 f16

  // casts
  cvt_f32_f16<<<16384, 256, 0, stream>>>(x, xh, 4194304);
  cvt_f32_f16<<<768,   256, 0, stream>>>(w_qkv, wqkv_h, 196608);
  cvt_f32_f16<<<256,   256, 0, stream>>>(w_proj, wproj_h, 65536);
  cvt_f32_f16<<<3,     256, 0, stream>>>(lepe_h, wlep_h, 576);
  cvt_f32_f16<<<3,     256, 0, stream>>>(lepe_v, wlep_h + 2304, 576);

  // qkv = x @ w_qkv^T -> window-major f16 regions (n-tile fast for L2 reuse)
  gemm_bt<1><<<dim3(12, 256), 256, 0, stream>>>(
      xh, wqkv_h, qkv_p, nullptr, nullptr, 32768, 1536, 512);

  // stripe attention + LePE -> attn_out token-major (xh region; xh dead)
  attn_lepe<<<8192, 256, 0, stream>>>(qkv_p, wlep_h, xh);

  // out = attn_out @ w_proj^T + b_proj -> f32
  gemm_bt<0><<<dim3(4, 256), 256, 0, stream>>>(
      xh, wproj_h, nullptr, out, b_proj, 32768, 512, 512);
}

// Round 9
// 184.188 us; speedup vs baseline: 1.2899x; 1.0548x over previous
//
#include <hip/hip_runtime.h>
#include <hip/hip_bf16.h>
#include <stdint.h>

// ---------- types ----------
typedef _Float16 half2v __attribute__((ext_vector_type(2)));
typedef _Float16 half8v __attribute__((ext_vector_type(8)));
typedef uint32_t u32x4  __attribute__((ext_vector_type(4)));
typedef float    f32x4  __attribute__((ext_vector_type(4)));

__device__ __forceinline__ unsigned short f2h(float f) {
  _Float16 h = (_Float16)f;
  return __builtin_bit_cast(unsigned short, h);
}
__device__ __forceinline__ half2v bch2(uint32_t u) {
  return __builtin_bit_cast(half2v, u);
}
__device__ __forceinline__ uint32_t pkrtz_u32(float a, float b) {
  return __builtin_bit_cast(uint32_t, __builtin_amdgcn_cvt_pkrtz(a, b));
}

// Window-major qkv layout. Element index (channel 0 of head n) for pixel (h,w),
// within one tensor's 32MB region (16M f16 elems; includes the half offset).
//  half 0 (horizontal stripes): [b][n][s=h>>3][w][qr=h&7][cc]
//  half 1 (vertical stripes):   [b][n][h][s=w>>3][qr=w&7][cc]  (s*256+qr*32 == w*32)
__device__ __forceinline__ int qkv_idx(int half, int b, int n, int h, int w) {
  int idx = half * 8388608 + (b * 8 + n) * 131072;
  idx += (half == 0) ? ((h >> 3) * 16384 + w * 256 + (h & 7) * 32)
                     : (h * 2048 + w * 32);
  return idx;
}

// async global->LDS, 16 bytes per lane. lbase must be wave-uniform.
#define GLOAD_LDS16(gsrc, lbase)                                          \
  __builtin_amdgcn_global_load_lds(                                       \
      (const __attribute__((address_space(1))) uint32_t*)(gsrc),          \
      (__attribute__((address_space(3))) uint32_t*)(lbase), 16, 0, 0)

// ---------- f32 -> f16 conversion (4 elems/thread) ----------
__global__ __launch_bounds__(256) void cvt_f32_f16(const float* __restrict__ in,
                                                   unsigned short* __restrict__ out,
                                                   int n4) {
  int i = blockIdx.x * 256 + threadIdx.x;
  if (i >= n4) return;
  float4 f = reinterpret_cast<const float4*>(in)[i];
  ushort4 u;
  u.x = f2h(f.x); u.y = f2h(f.y); u.z = f2h(f.z); u.w = f2h(f.w);
  reinterpret_cast<ushort4*>(out)[i] = u;
}

// ---------- f16 GEMM, C[m,n] = sum_k A[m,k]*B[n,k]  (A: MxK, B: NxK row-major)
// 128x128 tile, 4 waves (2x2), each wave 64x64 = 4x4 frags, MFMA 16x16x32 f16.
// 1D grid + bijective XCD swizzle (T1): wgid = (bid&7)*cpx + bid>>3, decomposed
// n-fast -> each XCD owns a contiguous m-band; its A-panels are fetched once
// into its private L2 and reused by all its n-tiles; B (<=1.5MB) L2-resident.
// T4 pipeline: double-buffered LDS, stage tile t+1 before compute of tile t,
// counted s_waitcnt vmcnt(4) (never 0 in loop) + raw s_barrier.
// Operand-swapped MFMA epilogue (lane holds 4 contiguous n at one m).
// LDS k-slot XOR swizzle (pre-swizzled global source; linear gload_lds dest).
// MODE 0: f32 out + bias, token-major (GEMM2).
// MODE 1: f16 out scattered to window-major qkv regions (GEMM1, N=1536).
template<int MODE>
__global__ __launch_bounds__(256) void gemm_bt(
    const unsigned short* __restrict__ A,
    const unsigned short* __restrict__ B,
    unsigned short* __restrict__ Cq,
    float* __restrict__ Cf,
    const float* __restrict__ bias,
    int M, int N, int K)
{
  __shared__ unsigned short As[2][128 * 32];
  __shared__ unsigned short Bs[2][128 * 32];
  const int tid  = threadIdx.x;
  // --- XCD-swizzled tile assignment (nwg % 8 == 0 -> bijective) ---
  const int gn   = N >> 7;
  const int cpx  = gridDim.x >> 3;
  const int bid  = blockIdx.x;
  const int wgid = (bid & 7) * cpx + (bid >> 3);
  const int m0   = (wgid / gn) * 128;
  const int n0   = (wgid % gn) * 128;
  const int wave = tid >> 6, lane = tid & 63;
  const int wr = wave >> 1, wc = wave & 1;
  const int sr = tid >> 2;                                // staging row 0..63
  const int sc = ((tid & 3) ^ ((tid >> 3) & 3)) * 8;      // pre-swizzled k-chunk
  const size_t aBase0 = (size_t)(m0 + sr) * K + sc;
  const size_t aBase1 = (size_t)(m0 + 64 + sr) * K + sc;
  const size_t bBase0 = (size_t)(n0 + sr) * K + sc;
  const size_t bBase1 = (size_t)(n0 + 64 + sr) * K + sc;
  // per-thread LDS dest is linear tid*16B within each buffer; wave-uniform base
  char* ldsA = (char*)(&As[0][0]) + (tid & ~63) * 16;
  char* ldsB = (char*)(&Bs[0][0]) + (tid & ~63) * 16;

#define STAGE_TILE(bsel, kofs)                                  \
  do {                                                          \
    GLOAD_LDS16(A + aBase0 + (kofs), ldsA + (bsel) * 8192);     \
    GLOAD_LDS16(A + aBase1 + (kofs), ldsA + (bsel) * 8192 + 4096); \
    GLOAD_LDS16(B + bBase0 + (kofs), ldsB + (bsel) * 8192);     \
    GLOAD_LDS16(B + bBase1 + (kofs), ldsB + (bsel) * 8192 + 4096); \
  } while (0)

  // prologue: stage tile 0 into buf0; acc-init overlaps the loads
  STAGE_TILE(0, 0);

  f32x4 acc[4][4];
  const f32x4 zero = {0.f, 0.f, 0.f, 0.f};
  #pragma unroll
  for (int i = 0; i < 4; ++i)
    #pragma unroll
    for (int j = 0; j < 4; ++j) acc[i][j] = zero;

  const int lr   = lane & 15;
  const int slot = (lane >> 4) ^ ((lr >> 1) & 3);   // swizzled k-slot (elems/8)

  auto compute = [&](const unsigned short* Asb, const unsigned short* Bsb) {
    half8v af[4], bfr[4];
    #pragma unroll
    for (int i = 0; i < 4; ++i)
      af[i] = *reinterpret_cast<const half8v*>(Asb + (wr * 64 + i * 16 + lr) * 32 + slot * 8);
    #pragma unroll
    for (int j = 0; j < 4; ++j)
      bfr[j] = *reinterpret_cast<const half8v*>(Bsb + (wc * 64 + j * 16 + lr) * 32 + slot * 8);
    __builtin_amdgcn_s_setprio(1);
    #pragma unroll
    for (int i = 0; i < 4; ++i)
      #pragma unroll
      for (int j = 0; j < 4; ++j)
        acc[i][j] = __builtin_amdgcn_mfma_f32_16x16x32_f16(bfr[j], af[i], acc[i][j], 0, 0, 0);
    __builtin_amdgcn_s_setprio(0);
  };

  const int nt = K >> 5;   // K/32 tiles
  for (int t = 0; t < nt - 1; ++t) {
    STAGE_TILE((t + 1) & 1, (t + 1) * 32);          // issue next-tile loads
    asm volatile("s_waitcnt vmcnt(4)" ::: "memory"); // tile t's 4 loads done;
                                                     // tile t+1's stay in flight
    __builtin_amdgcn_s_barrier();                    // tile t visible to all
    __builtin_amdgcn_sched_barrier(0);
    compute(&As[t & 1][0], &Bs[t & 1][0]);
    __builtin_amdgcn_s_barrier();                    // all done reading buf[t&1]
    __builtin_amdgcn_sched_barrier(0);
  }
  // epilogue tile: drain remaining loads
  asm volatile("s_waitcnt vmcnt(0)" ::: "memory");
  __builtin_amdgcn_s_barrier();
  __builtin_amdgcn_sched_barrier(0);
  compute(&As[(nt - 1) & 1][0], &Bs[(nt - 1) & 1][0]);
#undef STAGE_TILE

  // D layout (operand-swapped): row (n-dim) = (lane>>4)*4 + t, col (m-dim) = lane&15
  const int cr = (lane >> 4) * 4;   // channel offset (4 contiguous)
  const int cc = lane & 15;         // token offset

  if constexpr (MODE == 0) {
    #pragma unroll
    for (int j = 0; j < 4; ++j) {
      const int n = n0 + wc * 64 + j * 16 + cr;
      const float4 b4 = *reinterpret_cast<const float4*>(bias + n);
      #pragma unroll
      for (int i = 0; i < 4; ++i) {
        const int m = m0 + wr * 64 + i * 16 + cc;
        float4 r;
        r.x = acc[i][j][0] + b4.x;
        r.y = acc[i][j][1] + b4.y;
        r.z = acc[i][j][2] + b4.z;
        r.w = acc[i][j][3] + b4.w;
        *reinterpret_cast<float4*>(Cf + (size_t)m * N + n) = r;
      }
    }
  } else {
    const int mb   = m0 + wr * 64;    // token base (wave-uniform)
    const int btok = mb >> 12;
    const int htok = (mb >> 6) & 63;
    #pragma unroll
    for (int j = 0; j < 4; ++j) {
      const int nb    = n0 + wc * 64 + j * 16 + cr;  // 4 contiguous channels
      const int tq    = nb >> 9;                     // 0=q 1=k 2=v
      const int halfc = (nb >> 8) & 1;
      const int nn    = (nb & 255) >> 5;
      const int ch4   = nb & 31;
      int base = tq * 16777216 + halfc * 8388608 + (btok * 8 + nn) * 131072 + ch4;
      base += halfc ? (htok * 2048) : ((htok >> 3) * 16384 + (htok & 7) * 32);
      const int wstride = halfc ? 32 : 256;
      #pragma unroll
      for (int i = 0; i < 4; ++i) {
        const int wpix = i * 16 + cc;
        uint2 r;
        r.x = pkrtz_u32(acc[i][j][0], acc[i][j][1]);
        r.y = pkrtz_u32(acc[i][j][2], acc[i][j][3]);
        *reinterpret_cast<uint2*>(Cq + base + wpix * wstride) = r;
      }
    }
  }
}

// ---------- stripe attention + LePE, TWO windows per wave ----------
// qkvp: q (32MB) | k (32MB) | v (32MB), f16, window-major.
// wlep: f16 LePE weights [half][tap(9)][256].
// outp: token-major 32768 x 512 f16.
// Pairing: half 0 pairs adjacent columns (w, w+1) of one h-stripe;
//          half 1 pairs adjacent rows (h, h+1) of one w-stripe.
// Phase QK: lane=(qr,kr) computes both windows' logits (packed f16x2 weight).
// Phase PV/LePE/store: lane=(qr2, win, dgrp) with 16B vectors (8 ch).
__global__ __launch_bounds__(256) void attn_lepe(
    const unsigned short* __restrict__ qkvp,
    const unsigned short* __restrict__ wlep,
    unsigned short* __restrict__ outp)
{
  const int gw   = (int)((blockIdx.x * 256 + threadIdx.x) >> 6);  // pair index
  const int lane = threadIdx.x & 63;
  const int half = gw >> 14;
  const int id   = gw & 16383;
  const int b    = id >> 11;
  const int n    = (id >> 8) & 7;
  int h0, w0;
  if (half == 0) { h0 = ((id >> 5) & 7) * 8; w0 = (id & 31) * 2; }
  else           { h0 = ((id >> 3) & 31) * 2; w0 = (id & 7) * 8; }
  const int baseA = qkv_idx(half, b, n, h0, w0);
  const int dWin  = (half == 0) ? 256 : 2048;   // adjacent-window offset
  const int baseB = baseA + dWin;

  // ---- QK^T for both windows: lane = (qr, kr) ----
  const int qr = lane >> 3, kr = lane & 7;
  const unsigned short* qA = qkvp + baseA + qr * 32;
  const unsigned short* kA = qkvp + 16777216 + baseA + kr * 32;
  float sA = 0.f, sB = 0.f;
  #pragma unroll
  for (int c = 0; c < 4; ++c) {
    const u32x4 qa = *reinterpret_cast<const u32x4*>(qA + c * 8);
    const u32x4 ka = *reinterpret_cast<const u32x4*>(kA + c * 8);
    const u32x4 qb = *reinterpret_cast<const u32x4*>(qA + dWin + c * 8);
    const u32x4 kb = *reinterpret_cast<const u32x4*>(kA + dWin + c * 8);
    #pragma unroll
    for (int e = 0; e < 4; ++e) {
      sA = __builtin_amdgcn_fdot2(bch2(qa[e]), bch2(ka[e]), sA, false);
      sB = __builtin_amdgcn_fdot2(bch2(qb[e]), bch2(kb[e]), sB, false);
    }
  }
  const float scl = 0.17677669529663687f;  // 1/sqrt(32)
  const float pA = __expf(sA * scl);
  const float pB = __expf(sB * scl);
  float denA = pA, denB = pB;
  denA += __shfl_xor(denA, 1); denA += __shfl_xor(denA, 2); denA += __shfl_xor(denA, 4);
  denB += __shfl_xor(denB, 1); denB += __shfl_xor(denB, 2); denB += __shfl_xor(denB, 4);
  const float aAv = pA * __builtin_amdgcn_rcpf(denA);
  const float aBv = pB * __builtin_amdgcn_rcpf(denB);
  const uint32_t adu = pkrtz_u32(aAv, aBv);   // lo = winA, hi = winB

  // ---- PV: lane = (qr2, win, dgrp); 16B vectors over 8 channels ----
  const int dgrp = lane & 3;
  const int win  = (lane >> 2) & 1;
  const int qr2  = lane >> 3;
  const int d0   = dgrp * 8;
  const int mybase = win ? baseB : baseA;
  const unsigned short* vwin = qkvp + 33554432 + mybase;

  half2v o01 = {0,0}, o23 = {0,0}, o45 = {0,0}, o67 = {0,0};
  #pragma unroll
  for (int k = 0; k < 8; ++k) {
    const uint32_t pairw = (uint32_t)__shfl((int)adu, qr2 * 8 + k);
    const half2v ph = bch2(pairw);
    const _Float16 av = win ? ph.y : ph.x;
    const half2v ak2 = {av, av};
    const u32x4 vv = *reinterpret_cast<const u32x4*>(vwin + k * 32 + d0);
    o01 += ak2 * bch2(vv[0]);
    o23 += ak2 * bch2(vv[1]);
    o45 += ak2 * bch2(vv[2]);
    o67 += ak2 * bch2(vv[3]);
  }

  // ---- LePE: depthwise 3x3 on v (zero-pad SAME) at this lane's pixel ----
  const int hq = (half == 0) ? (h0 + qr2) : (h0 + win);
  const int wq = (half == 0) ? (w0 + win) : (w0 + qr2);
  const unsigned short* vplane = qkvp + 33554432;
  const unsigned short* wl = wlep + half * 2304 + n * 32 + d0;
  half2v l01 = {0,0}, l23 = {0,0}, l45 = {0,0}, l67 = {0,0};
  #pragma unroll
  for (int dy = -1; dy <= 1; ++dy) {
    #pragma unroll
    for (int dx = -1; dx <= 1; ++dx) {
      const int hh = hq + dy, ww = wq + dx;
      u32x4 vv = {0u, 0u, 0u, 0u};
      if ((unsigned)hh < 64u && (unsigned)ww < 64u)
        vv = *reinterpret_cast<const u32x4*>(vplane + qkv_idx(half, b, n, hh, ww) + d0);
      const u32x4 wt = *reinterpret_cast<const u32x4*>(wl + ((dy + 1) * 3 + dx + 1) * 256);
      l01 += bch2(wt[0]) * bch2(vv[0]);
      l23 += bch2(wt[1]) * bch2(vv[1]);
      l45 += bch2(wt[2]) * bch2(vv[2]);
      l67 += bch2(wt[3]) * bch2(vv[3]);
    }
  }

  // ---- store token-major for GEMM2 (16B per lane) ----
  const int m = b * 4096 + hq * 64 + wq;
  const int chan0 = half * 256 + n * 32;
  u32x4 r;
  r[0] = __builtin_bit_cast(uint32_t, (half2v)(o01 + l01));
  r[1] = __builtin_bit_cast(uint32_t, (half2v)(o23 + l23));
  r[2] = __builtin_bit_cast(uint32_t, (half2v)(o45 + l45));
  r[3] = __builtin_bit_cast(uint32_t, (half2v)(o67 + l67));
  *reinterpret_cast<u32x4*>(outp + (size_t)m * 512 + chan0 + d0) = r;
}

// ---------- launch ----------
extern "C" void kernel_launch(void* const* d_in, const int* in_sizes, int n_in,
                              void* d_out, int out_size, void* d_ws, size_t ws_size,
                              hipStream_t stream) {
  const float* x      = (const float*)d_in[0];   // (8, 4096, 512)
  const float* w_qkv  = (const float*)d_in[1];   // (1536, 512)
  const float* w_proj = (const float*)d_in[2];   // (512, 512)
  const float* b_proj = (const float*)d_in[3];   // (512,)
  const float* lepe_h = (const float*)d_in[4];   // (3,3,1,256)
  const float* lepe_v = (const float*)d_in[5];   // (3,3,1,256)
  float* out = (float*)d_out;                    // (8, 4096, 512) f32

  char* ws = (char*)d_ws;
  unsigned short* qkv_p   = (unsigned short*)ws;                 // 96MB: q|k|v window-major
  unsigned short* xh      = (unsigned short*)(ws + 100663296);   // 32MB: x f16; reused as attn_out
  unsigned short* wqkv_h  = (unsigned short*)(ws + 134217728);   // 1536*512 f16
  unsigned short* wproj_h = (unsigned short*)(ws + 135790592);   // 512*512 f16
  unsigned short* wlep_h  = (unsigned short*)(ws + 136314880);   // 2*9*256 f16

  // casts
  cvt_f32_f16<<<16384, 256, 0, stream>>>(x, xh, 4194304);
  cvt_f32_f16<<<768,   256, 0, stream>>>(w_qkv, wqkv_h, 196608);
  cvt_f32_f16<<<256,   256, 0, stream>>>(w_proj, wproj_h, 65536);
  cvt_f32_f16<<<3,     256, 0, stream>>>(lepe_h, wlep_h, 576);
  cvt_f32_f16<<<3,     256, 0, stream>>>(lepe_v, wlep_h + 2304, 576);

  // qkv = x @ w_qkv^T -> window-major f16 regions (XCD-swizzled 1D grid)
  gemm_bt<1><<<3072, 256, 0, stream>>>(
      xh, wqkv_h, qkv_p, nullptr, nullptr, 32768, 1536, 512);

  // stripe attention + LePE -> attn_out token-major (xh region; xh dead)
  attn_lepe<<<8192, 256, 0, stream>>>(qkv_p, wlep_h, xh);

  // out = attn_out @ w_proj^T + b_proj -> f32
  gemm_bt<0><<<1024, 256, 0, stream>>>(
      xh, wproj_h, nullptr, out, b_proj, 32768, 512, 512);
}